// Round 1
// baseline (80.050 us; speedup 1.0000x reference)
//
#include <hip/hip_runtime.h>

#define N_ROWS 8192
#define N_COLS 10000
#define MAX_MARGIN_V (-25.0f)
#define MIN_MARGIN_V (50.0f)

// ws layout (floats): ws[0] = S_all, ws[1] = T_plus, ws[2] = T_hinge

__global__ void __launch_bounds__(256) hinge_sum_all(const float4* __restrict__ in,
                                                     float* __restrict__ ws,
                                                     long long n4) {
    float acc = 0.0f;
    long long idx = (long long)blockIdx.x * blockDim.x + threadIdx.x;
    long long stride = (long long)gridDim.x * blockDim.x;
    for (long long i = idx; i < n4; i += stride) {
        float4 v = in[i];
        acc += fmaxf(v.x - MAX_MARGIN_V, 0.0f);
        acc += fmaxf(v.y - MAX_MARGIN_V, 0.0f);
        acc += fmaxf(v.z - MAX_MARGIN_V, 0.0f);
        acc += fmaxf(v.w - MAX_MARGIN_V, 0.0f);
    }
    // wave-64 reduction
    #pragma unroll
    for (int off = 32; off > 0; off >>= 1) acc += __shfl_down(acc, off, 64);
    __shared__ float wsum[4];  // 256 threads / 64 lanes
    int lane = threadIdx.x & 63;
    int wid = threadIdx.x >> 6;
    if (lane == 0) wsum[wid] = acc;
    __syncthreads();
    if (threadIdx.x == 0) {
        float s = wsum[0] + wsum[1] + wsum[2] + wsum[3];
        atomicAdd(&ws[0], s);
    }
}

__global__ void __launch_bounds__(256) hinge_targets(const float* __restrict__ in,
                                                     const int* __restrict__ tgt,
                                                     float* __restrict__ ws) {
    int row = blockIdx.x * blockDim.x + threadIdx.x;
    float plus = 0.0f, hinge = 0.0f;
    if (row < N_ROWS) {
        int t = tgt[row];
        float x = in[(long long)row * N_COLS + t];
        plus  = fmaxf(x - MAX_MARGIN_V, 0.0f);   // the incorrectly-counted non-target term
        hinge = fmaxf(MIN_MARGIN_V - x, 0.0f);   // the true target term
    }
    #pragma unroll
    for (int off = 32; off > 0; off >>= 1) {
        plus  += __shfl_down(plus, off, 64);
        hinge += __shfl_down(hinge, off, 64);
    }
    __shared__ float sp[4], sh[4];
    int lane = threadIdx.x & 63;
    int wid = threadIdx.x >> 6;
    if (lane == 0) { sp[wid] = plus; sh[wid] = hinge; }
    __syncthreads();
    if (threadIdx.x == 0) {
        atomicAdd(&ws[1], sp[0] + sp[1] + sp[2] + sp[3]);
        atomicAdd(&ws[2], sh[0] + sh[1] + sh[2] + sh[3]);
    }
}

__global__ void hinge_finalize(const float* __restrict__ ws, float* __restrict__ out) {
    if (threadIdx.x == 0 && blockIdx.x == 0) {
        const float inv_n = 1.0f / (float)N_ROWS;
        float s_all = ws[0], t_plus = ws[1], t_hinge = ws[2];
        float s_inter = s_all - t_plus;                 // non-target-only sum
        out[0] = (s_inter + t_hinge) * inv_n;           // loss_m.sum()/n
        out[1] = s_inter * inv_n;                       // loss_inter.sum()/n
    }
}

extern "C" void kernel_launch(void* const* d_in, const int* in_sizes, int n_in,
                              void* d_out, int out_size, void* d_ws, size_t ws_size,
                              hipStream_t stream) {
    const float* inputs = (const float*)d_in[0];
    const int* targets = (const int*)d_in[1];
    float* out = (float*)d_out;
    float* ws = (float*)d_ws;

    // zero the 3 accumulators (allowed under graph capture as a memset node)
    hipMemsetAsync(ws, 0, 3 * sizeof(float), stream);

    const long long n4 = (long long)N_ROWS * N_COLS / 4;  // 20,480,000 float4s
    const int block = 256;
    const int grid = 2048;  // 256 CU × 8 blocks; grid-stride covers the rest
    hinge_sum_all<<<grid, block, 0, stream>>>((const float4*)inputs, ws, n4);

    hinge_targets<<<(N_ROWS + block - 1) / block, block, 0, stream>>>(inputs, targets, ws);

    hinge_finalize<<<1, 64, 0, stream>>>(ws, out);
}